// Round 4
// baseline (209.323 us; speedup 1.0000x reference)
//
#include <hip/hip_runtime.h>
#include <hip/hip_bf16.h>

typedef __attribute__((ext_vector_type(8))) short bf16x8;
typedef __attribute__((ext_vector_type(4))) short s16x4;
typedef __attribute__((ext_vector_type(4))) float f32x4;

__device__ __forceinline__ short f2bf(float f) {
    unsigned int u = __builtin_bit_cast(unsigned int, f);
    u += 0x7fffu + ((u >> 16) & 1u);
    return (short)(u >> 16);
}
__device__ __forceinline__ float bf2f(short s) {
    unsigned int u = ((unsigned int)(unsigned short)s) << 16;
    return __builtin_bit_cast(float, u);
}

#define GLDS(g, l) __builtin_amdgcn_global_load_lds( \
    (__attribute__((address_space(1))) void*)(g),    \
    (__attribute__((address_space(3))) void*)(l), 16, 0, 0)

// ---------------- fp32 -> bf16 convert ----------------
__global__ __launch_bounds__(256) void cvt_kernel(const float* __restrict__ in,
                                                  short* __restrict__ out, int n4) {
    int i = blockIdx.x * 256 + threadIdx.x;
    if (i >= n4) return;
    float4 v = reinterpret_cast<const float4*>(in)[i];
    s16x4 r = { f2bf(v.x), f2bf(v.y), f2bf(v.z), f2bf(v.w) };
    reinterpret_cast<s16x4*>(out)[i] = r;
}

#define LDP 72

// ---------------- QKV GEMM (+RoPE epilogue), global_load_lds staging ----------------
__global__ __launch_bounds__(256) void gemm_qkv_rope(
    const short* __restrict__ X, const short* __restrict__ W,
    const float* __restrict__ cosT, const float* __restrict__ sinT,
    short* __restrict__ Qo, short* __restrict__ Ko, short* __restrict__ Vo) {
    __shared__ short As[128 * 64];   // linear, row-major [128][64]
    __shared__ short Bs[128 * 64];
    const int tid = threadIdx.x;
    const int lane = tid & 63;
    const int w = tid >> 6;
    const int lo = lane & 15, hi = lane >> 4;
    const int wr = w >> 1, wc = w & 1;
    const int m0 = blockIdx.y * 128;
    const int n0 = blockIdx.x * 128;
    const int K = 1024;

    f32x4 acc[4][4];
#pragma unroll
    for (int i = 0; i < 4; i++)
#pragma unroll
        for (int j = 0; j < 4; j++) acc[i][j] = {0.f, 0.f, 0.f, 0.f};

    // staging geometry: per call a wave covers rows [it*32 + w*8, +8), lane>>3 = row, lane&7 = 16B chunk
    const int srow = w * 8 + (lane >> 3);
    const int sc8 = (lane & 7) * 8;
    const short* gA = X + (size_t)(m0 + srow) * K + sc8;
    const short* gB = W + (size_t)(n0 + srow) * K + sc8;

    for (int k0 = 0; k0 < K; k0 += 64) {
        __syncthreads();
#pragma unroll
        for (int it = 0; it < 4; it++)
            GLDS(gA + k0 + (size_t)it * 32 * K, (char*)As + it * 4096 + w * 1024);
#pragma unroll
        for (int it = 0; it < 4; it++)
            GLDS(gB + k0 + (size_t)it * 32 * K, (char*)Bs + it * 4096 + w * 1024);
        __syncthreads();
#pragma unroll
        for (int kk = 0; kk < 2; kk++) {
            bf16x8 a[4], b[4];
#pragma unroll
            for (int mi = 0; mi < 4; mi++)
                a[mi] = *reinterpret_cast<const bf16x8*>(
                    &As[(wr * 64 + mi * 16 + lo) * 64 + kk * 32 + hi * 8]);
#pragma unroll
            for (int ni = 0; ni < 4; ni++)
                b[ni] = *reinterpret_cast<const bf16x8*>(
                    &Bs[(wc * 64 + ni * 16 + lo) * 64 + kk * 32 + hi * 8]);
#pragma unroll
            for (int mi = 0; mi < 4; mi++)
#pragma unroll
                for (int ni = 0; ni < 4; ni++)
                    acc[mi][ni] = __builtin_amdgcn_mfma_f32_16x16x32_bf16(
                        a[mi], b[ni], acc[mi][ni], 0, 0, 0);
        }
    }

    const int region = n0 >> 10;
#pragma unroll
    for (int mi = 0; mi < 4; mi++) {
#pragma unroll
        for (int r = 0; r < 4; r++) {
            const int m = m0 + wr * 64 + mi * 16 + (hi << 2) + r;
            const int b_ = m >> 11;
            const int s_ = m & 2047;
#pragma unroll
            for (int ni = 0; ni < 4; ni++) {
                float v = acc[mi][ni][r];
                const int n = n0 + wc * 64 + ni * 16 + lo;
                const int c = n & 1023;
                const int h = c >> 6;
                const int d = c & 63;
                const size_t oidx = ((size_t)(b_ * 16 + h) * 2048 + s_) * 64 + d;
                if (region == 2) {
                    Vo[oidx] = f2bf(v);
                } else {
                    float other = __shfl_xor(v, 1, 64);
                    const int i2 = d >> 1;
                    float cs = cosT[s_ * 32 + i2];
                    float sn = sinT[s_ * 32 + i2];
                    float outv = (d & 1) ? (v * cs + other * sn) : (v * cs - other * sn);
                    if (region == 0) {
                        Qo[oidx] = f2bf(outv * 0.125f);
                    } else {
                        Ko[oidx] = f2bf(outv);
                    }
                }
            }
        }
    }
}

// ---------------- Flash attention (causal, paired q-tiles, KV-parity split) ----------
// Partial outputs: Opart[z][bh][s][64] bf16 (unnormalized), ml[z][bh][s][2] f32 (m,l).
__device__ __forceinline__ void attn_tile_compute(
    const bf16x8 q0, const bf16x8 q1,
    const short (*Ks)[LDP], const short (*Vts)[LDP], short (*Pw)[LDP],
    const int lane, const int w, const bool diag,
    float* __restrict__ m_r, float* __restrict__ l_r, f32x4* __restrict__ o_acc) {
    const int lo = lane & 15, hi = lane >> 4;

    f32x4 sc[4];
#pragma unroll
    for (int nb = 0; nb < 4; nb++) sc[nb] = {0.f, 0.f, 0.f, 0.f};
#pragma unroll
    for (int nb = 0; nb < 4; nb++) {
        bf16x8 b0 = *reinterpret_cast<const bf16x8*>(&Ks[nb * 16 + lo][hi * 8]);
        sc[nb] = __builtin_amdgcn_mfma_f32_16x16x32_bf16(q0, b0, sc[nb], 0, 0, 0);
        bf16x8 b1 = *reinterpret_cast<const bf16x8*>(&Ks[nb * 16 + lo][32 + hi * 8]);
        sc[nb] = __builtin_amdgcn_mfma_f32_16x16x32_bf16(q1, b1, sc[nb], 0, 0, 0);
    }
    if (diag) {
        const int s_ = w * 16 + (hi << 2);
#pragma unroll
        for (int nb = 0; nb < 4; nb++) {
            const int t_ = nb * 16 + lo;
#pragma unroll
            for (int r = 0; r < 4; r++)
                if (t_ > s_ + r) sc[nb][r] = -1e30f;
        }
    }

    float p[4][4];
#pragma unroll
    for (int r = 0; r < 4; r++) {
        float mx = fmaxf(fmaxf(sc[0][r], sc[1][r]), fmaxf(sc[2][r], sc[3][r]));
#pragma unroll
        for (int off = 1; off < 16; off <<= 1) mx = fmaxf(mx, __shfl_xor(mx, off, 64));
        const float mnew = fmaxf(m_r[r], mx);
        const float alpha = __expf(m_r[r] - mnew);
        m_r[r] = mnew;
        float rs = 0.f;
#pragma unroll
        for (int nb = 0; nb < 4; nb++) {
            float e = __expf(sc[nb][r] - mnew);
            p[nb][r] = e;
            rs += e;
        }
#pragma unroll
        for (int off = 1; off < 16; off <<= 1) rs += __shfl_xor(rs, off, 64);
        l_r[r] = l_r[r] * alpha + rs;
#pragma unroll
        for (int db = 0; db < 4; db++) o_acc[db][r] *= alpha;
    }
#pragma unroll
    for (int nb = 0; nb < 4; nb++)
#pragma unroll
        for (int r = 0; r < 4; r++)
            Pw[(hi << 2) + r][nb * 16 + lo] = f2bf(p[nb][r]);
#pragma unroll
    for (int kk = 0; kk < 2; kk++) {
        bf16x8 pa = *reinterpret_cast<const bf16x8*>(&Pw[lo][kk * 32 + hi * 8]);
#pragma unroll
        for (int db = 0; db < 4; db++) {
            const int d = db * 16 + lo;
            const int tsw = (kk * 32 + hi * 8) ^ ((((d >> 3) & 7)) << 3);
            bf16x8 vb = *reinterpret_cast<const bf16x8*>(&Vts[d][tsw]);
            o_acc[db] = __builtin_amdgcn_mfma_f32_16x16x32_bf16(pa, vb, o_acc[db], 0, 0, 0);
        }
    }
}

__global__ __launch_bounds__(256) void attn_kernel(
    const short* __restrict__ Q, const short* __restrict__ K,
    const short* __restrict__ V, short* __restrict__ Opart,
    float* __restrict__ mlb) {
    __shared__ short Ks[64][LDP];
    __shared__ short Vts[64][LDP];
    __shared__ short Ps[4][16][LDP];

    const int tid = threadIdx.x;
    const int lane = tid & 63;
    const int w = tid >> 6;
    const int lo = lane & 15, hi = lane >> 4;
    const int pi = blockIdx.x;          // 0..15
    const int qa = pi, qb = 31 - pi;
    const int bh = blockIdx.y;
    const int z = blockIdx.z;           // KV parity
    const size_t base = (size_t)bh * 2048 * 64;

    // Q-hoist: stage both Q tiles through Ks, keep fragments in registers
    bf16x8 qaf0, qaf1, qbf0, qbf1;
    {
        const int row = tid >> 2, cb = (tid & 3) * 16;
        const short* srcA = Q + base + (size_t)(qa * 64 + row) * 64 + cb;
        *reinterpret_cast<bf16x8*>(&Ks[row][cb]) = *reinterpret_cast<const bf16x8*>(srcA);
        *reinterpret_cast<bf16x8*>(&Ks[row][cb + 8]) = *reinterpret_cast<const bf16x8*>(srcA + 8);
        __syncthreads();
        qaf0 = *reinterpret_cast<const bf16x8*>(&Ks[w * 16 + lo][hi * 8]);
        qaf1 = *reinterpret_cast<const bf16x8*>(&Ks[w * 16 + lo][32 + hi * 8]);
        __syncthreads();
        const short* srcB = Q + base + (size_t)(qb * 64 + row) * 64 + cb;
        *reinterpret_cast<bf16x8*>(&Ks[row][cb]) = *reinterpret_cast<const bf16x8*>(srcB);
        *reinterpret_cast<bf16x8*>(&Ks[row][cb + 8]) = *reinterpret_cast<const bf16x8*>(srcB + 8);
        __syncthreads();
        qbf0 = *reinterpret_cast<const bf16x8*>(&Ks[w * 16 + lo][hi * 8]);
        qbf1 = *reinterpret_cast<const bf16x8*>(&Ks[w * 16 + lo][32 + hi * 8]);
    }

    float m_a[4], l_a[4], m_b[4], l_b[4];
    f32x4 o_a[4], o_b[4];
#pragma unroll
    for (int r = 0; r < 4; r++) { m_a[r] = -1e30f; l_a[r] = 0.f; m_b[r] = -1e30f; l_b[r] = 0.f; }
#pragma unroll
    for (int db = 0; db < 4; db++) { o_a[db] = {0.f, 0.f, 0.f, 0.f}; o_b[db] = {0.f, 0.f, 0.f, 0.f}; }

    for (int j = z; j <= qb; j += 2) {
        const int jbase = j * 64;
        __syncthreads();   // protects qbf read (iter 1) / prior compute
        {
            const int row = tid >> 2, cb = (tid & 3) * 16;
            const short* src = K + base + (size_t)(jbase + row) * 64 + cb;
            *reinterpret_cast<bf16x8*>(&Ks[row][cb]) = *reinterpret_cast<const bf16x8*>(src);
            *reinterpret_cast<bf16x8*>(&Ks[row][cb + 8]) = *reinterpret_cast<const bf16x8*>(src + 8);
        }
#pragma unroll
        for (int half = 0; half < 2; half++) {
            const int kv = (tid >> 3) + half * 32;
            const int db8 = (tid & 7) * 8;
            const int swz = (tid & 7) << 3;
            bf16x8 v = *reinterpret_cast<const bf16x8*>(V + base + (size_t)(jbase + kv) * 64 + db8);
            const int tsw = kv ^ swz;
#pragma unroll
            for (int i = 0; i < 8; i++) Vts[db8 + i][tsw] = v[i];
        }
        __syncthreads();

        attn_tile_compute(qbf0, qbf1, Ks, Vts, Ps[w], lane, w, j == qb, m_b, l_b, o_b);
        if (j <= qa)
            attn_tile_compute(qaf0, qaf1, Ks, Vts, Ps[w], lane, w, j == qa, m_a, l_a, o_a);
    }

    const size_t idxb = (size_t)bh * 2048;
    const size_t zoff = (size_t)z * 65536;
#pragma unroll
    for (int r = 0; r < 4; r++) {
        const int ra = qa * 64 + w * 16 + (hi << 2) + r;
        const int rb = qb * 64 + w * 16 + (hi << 2) + r;
#pragma unroll
        for (int db = 0; db < 4; db++) {
            Opart[(zoff + idxb + ra) * 64 + db * 16 + lo] = f2bf(o_a[db][r]);
            Opart[(zoff + idxb + rb) * 64 + db * 16 + lo] = f2bf(o_b[db][r]);
        }
    }
    if (lo == 0) {
#pragma unroll
        for (int r = 0; r < 4; r++) {
            const int ra = qa * 64 + w * 16 + (hi << 2) + r;
            const int rb = qb * 64 + w * 16 + (hi << 2) + r;
            mlb[(zoff + idxb + ra) * 2] = m_a[r];
            mlb[(zoff + idxb + ra) * 2 + 1] = l_a[r];
            mlb[(zoff + idxb + rb) * 2] = m_b[r];
            mlb[(zoff + idxb + rb) * 2 + 1] = l_b[r];
        }
    }
}

// ---------------- merge z-partitions -> Ob (4096,1024) bf16 ----------------
__global__ __launch_bounds__(256) void attn_merge(
    const short* __restrict__ Op, const float* __restrict__ mlb,
    short* __restrict__ Ob) {
    const int idx = blockIdx.x * 4 + (threadIdx.x >> 6);   // row in [0,65536)
    const int lane = threadIdx.x & 63;
    const int bh = idx >> 11, s = idx & 2047;
    const int b_ = bh >> 4, h = bh & 15;
    const float m0 = mlb[(size_t)idx * 2], l0 = mlb[(size_t)idx * 2 + 1];
    const float m1 = mlb[((size_t)65536 + idx) * 2], l1 = mlb[((size_t)65536 + idx) * 2 + 1];
    const float M = fmaxf(m0, m1);
    const float w0 = __expf(m0 - M), w1 = __expf(m1 - M);
    const float dn = 1.f / (w0 * l0 + w1 * l1);
    const float o0 = bf2f(Op[(size_t)idx * 64 + lane]);
    const float o1 = bf2f(Op[((size_t)65536 + idx) * 64 + lane]);
    Ob[((size_t)(b_ * 2048 + s)) * 1024 + h * 64 + lane] = f2bf((w0 * o0 + w1 * o1) * dn);
}

// ---------------- Out GEMM, global_load_lds staging ----------------
__global__ __launch_bounds__(256) void gemm_out(
    const short* __restrict__ A, const short* __restrict__ W,
    float* __restrict__ C) {
    __shared__ short As[128 * 64];
    __shared__ short Bs[128 * 64];
    const int tid = threadIdx.x;
    const int lane = tid & 63;
    const int w = tid >> 6;
    const int lo = lane & 15, hi = lane >> 4;
    const int wr = w >> 1, wc = w & 1;
    const int m0 = blockIdx.y * 128;
    const int n0 = blockIdx.x * 128;
    const int K = 1024;

    f32x4 acc[4][4];
#pragma unroll
    for (int i = 0; i < 4; i++)
#pragma unroll
        for (int j = 0; j < 4; j++) acc[i][j] = {0.f, 0.f, 0.f, 0.f};

    const int srow = w * 8 + (lane >> 3);
    const int sc8 = (lane & 7) * 8;
    const short* gA = A + (size_t)(m0 + srow) * K + sc8;
    const short* gB = W + (size_t)(n0 + srow) * K + sc8;

    for (int k0 = 0; k0 < K; k0 += 64) {
        __syncthreads();
#pragma unroll
        for (int it = 0; it < 4; it++)
            GLDS(gA + k0 + (size_t)it * 32 * K, (char*)As + it * 4096 + w * 1024);
#pragma unroll
        for (int it = 0; it < 4; it++)
            GLDS(gB + k0 + (size_t)it * 32 * K, (char*)Bs + it * 4096 + w * 1024);
        __syncthreads();
#pragma unroll
        for (int kk = 0; kk < 2; kk++) {
            bf16x8 a[4], b[4];
#pragma unroll
            for (int mi = 0; mi < 4; mi++)
                a[mi] = *reinterpret_cast<const bf16x8*>(
                    &As[(wr * 64 + mi * 16 + lo) * 64 + kk * 32 + hi * 8]);
#pragma unroll
            for (int ni = 0; ni < 4; ni++)
                b[ni] = *reinterpret_cast<const bf16x8*>(
                    &Bs[(wc * 64 + ni * 16 + lo) * 64 + kk * 32 + hi * 8]);
#pragma unroll
            for (int mi = 0; mi < 4; mi++)
#pragma unroll
                for (int ni = 0; ni < 4; ni++)
                    acc[mi][ni] = __builtin_amdgcn_mfma_f32_16x16x32_bf16(
                        a[mi], b[ni], acc[mi][ni], 0, 0, 0);
        }
    }

#pragma unroll
    for (int mi = 0; mi < 4; mi++) {
#pragma unroll
        for (int r = 0; r < 4; r++) {
            const int m = m0 + wr * 64 + mi * 16 + (hi << 2) + r;
#pragma unroll
            for (int ni = 0; ni < 4; ni++) {
                const int n = n0 + wc * 64 + ni * 16 + lo;
                C[(size_t)m * 1024 + n] = acc[mi][ni][r];
            }
        }
    }
}

extern "C" void kernel_launch(void* const* d_in, const int* in_sizes, int n_in,
                              void* d_out, int out_size, void* d_ws, size_t ws_size,
                              hipStream_t stream) {
    const float* x = (const float*)d_in[0];
    const float* wQKV = (const float*)d_in[1];
    const float* wOut = (const float*)d_in[2];
    const float* cosT = (const float*)d_in[3];
    const float* sinT = (const float*)d_in[4];
    float* out = (float*)d_out;

    char* ws = (char*)d_ws;
    const size_t MB = 1024 * 1024;
    short* xb    = (short*)(ws);             // 8MB
    short* wqkvb = (short*)(ws + 8 * MB);    // 6MB
    short* woutb = (short*)(ws + 14 * MB);   // 2MB
    short* Qbuf  = (short*)(ws + 16 * MB);   // 8MB
    short* Kbuf  = (short*)(ws + 24 * MB);   // 8MB
    short* Vbuf  = (short*)(ws + 32 * MB);   // 8MB
    short* Obuf  = (short*)(ws + 40 * MB);   // 8MB (merged attn out, bf16)
    short* Opart = (short*)(ws + 48 * MB);   // 16MB (2 partitions)
    float* mlbuf = (float*)(ws + 64 * MB);   // 1MB
    // total 65MB

    cvt_kernel<<<4096, 256, 0, stream>>>(x, xb, 1048576);
    cvt_kernel<<<3072, 256, 0, stream>>>(wQKV, wqkvb, 786432);
    cvt_kernel<<<1024, 256, 0, stream>>>(wOut, woutb, 262144);

    gemm_qkv_rope<<<dim3(24, 32), 256, 0, stream>>>(xb, wqkvb, cosT, sinT, Qbuf, Kbuf, Vbuf);
    attn_kernel<<<dim3(16, 32, 2), 256, 0, stream>>>(Qbuf, Kbuf, Vbuf, Opart, mlbuf);
    attn_merge<<<16384, 256, 0, stream>>>(Opart, mlbuf, Obuf);
    gemm_out<<<dim3(8, 32), 256, 0, stream>>>(Obuf, woutb, out);
}

// Round 5
// 170.083 us; speedup vs baseline: 1.2307x; 1.2307x over previous
//
#include <hip/hip_runtime.h>
#include <hip/hip_bf16.h>

typedef __attribute__((ext_vector_type(8))) short bf16x8;
typedef __attribute__((ext_vector_type(4))) short s16x4;
typedef __attribute__((ext_vector_type(4))) float f32x4;

__device__ __forceinline__ short f2bf(float f) {
    unsigned int u = __builtin_bit_cast(unsigned int, f);
    u += 0x7fffu + ((u >> 16) & 1u);
    return (short)(u >> 16);
}

#define GLDS(g, l) __builtin_amdgcn_global_load_lds( \
    (__attribute__((address_space(1))) void*)(g),    \
    (__attribute__((address_space(3))) void*)(l), 16, 0, 0)

// ---------------- fp32 -> bf16 convert ----------------
__global__ __launch_bounds__(256) void cvt_kernel(const float* __restrict__ in,
                                                  short* __restrict__ out, int n4) {
    int i = blockIdx.x * 256 + threadIdx.x;
    if (i >= n4) return;
    float4 v = reinterpret_cast<const float4*>(in)[i];
    s16x4 r = { f2bf(v.x), f2bf(v.y), f2bf(v.z), f2bf(v.w) };
    reinterpret_cast<s16x4*>(out)[i] = r;
}

#define LDP 72

// ---------------- QKV GEMM (+RoPE epilogue), global_load_lds staging ----------------
__global__ __launch_bounds__(256) void gemm_qkv_rope(
    const short* __restrict__ X, const short* __restrict__ W,
    const float* __restrict__ cosT, const float* __restrict__ sinT,
    short* __restrict__ Qo, short* __restrict__ Ko, short* __restrict__ Vo) {
    __shared__ short As[128 * 64];   // linear, row-major [128][64]
    __shared__ short Bs[128 * 64];
    const int tid = threadIdx.x;
    const int lane = tid & 63;
    const int w = tid >> 6;
    const int lo = lane & 15, hi = lane >> 4;
    const int wr = w >> 1, wc = w & 1;
    const int m0 = blockIdx.y * 128;
    const int n0 = blockIdx.x * 128;
    const int K = 1024;

    f32x4 acc[4][4];
#pragma unroll
    for (int i = 0; i < 4; i++)
#pragma unroll
        for (int j = 0; j < 4; j++) acc[i][j] = {0.f, 0.f, 0.f, 0.f};

    const int srow = w * 8 + (lane >> 3);
    const int sc8 = (lane & 7) * 8;
    const short* gA = X + (size_t)(m0 + srow) * K + sc8;
    const short* gB = W + (size_t)(n0 + srow) * K + sc8;

    for (int k0 = 0; k0 < K; k0 += 64) {
        __syncthreads();
#pragma unroll
        for (int it = 0; it < 4; it++)
            GLDS(gA + k0 + (size_t)it * 32 * K, (char*)As + it * 4096 + w * 1024);
#pragma unroll
        for (int it = 0; it < 4; it++)
            GLDS(gB + k0 + (size_t)it * 32 * K, (char*)Bs + it * 4096 + w * 1024);
        __syncthreads();
#pragma unroll
        for (int kk = 0; kk < 2; kk++) {
            bf16x8 a[4], b[4];
#pragma unroll
            for (int mi = 0; mi < 4; mi++)
                a[mi] = *reinterpret_cast<const bf16x8*>(
                    &As[(wr * 64 + mi * 16 + lo) * 64 + kk * 32 + hi * 8]);
#pragma unroll
            for (int ni = 0; ni < 4; ni++)
                b[ni] = *reinterpret_cast<const bf16x8*>(
                    &Bs[(wc * 64 + ni * 16 + lo) * 64 + kk * 32 + hi * 8]);
#pragma unroll
            for (int mi = 0; mi < 4; mi++)
#pragma unroll
                for (int ni = 0; ni < 4; ni++)
                    acc[mi][ni] = __builtin_amdgcn_mfma_f32_16x16x32_bf16(
                        a[mi], b[ni], acc[mi][ni], 0, 0, 0);
        }
    }

    const int region = n0 >> 10;
#pragma unroll
    for (int mi = 0; mi < 4; mi++) {
#pragma unroll
        for (int r = 0; r < 4; r++) {
            const int m = m0 + wr * 64 + mi * 16 + (hi << 2) + r;
            const int b_ = m >> 11;
            const int s_ = m & 2047;
#pragma unroll
            for (int ni = 0; ni < 4; ni++) {
                float v = acc[mi][ni][r];
                const int n = n0 + wc * 64 + ni * 16 + lo;
                const int c = n & 1023;
                const int h = c >> 6;
                const int d = c & 63;
                const size_t oidx = ((size_t)(b_ * 16 + h) * 2048 + s_) * 64 + d;
                if (region == 2) {
                    Vo[oidx] = f2bf(v);
                } else {
                    float other = __shfl_xor(v, 1, 64);
                    const int i2 = d >> 1;
                    float cs = cosT[s_ * 32 + i2];
                    float sn = sinT[s_ * 32 + i2];
                    float outv = (d & 1) ? (v * cs + other * sn) : (v * cs - other * sn);
                    if (region == 0) {
                        Qo[oidx] = f2bf(outv * 0.125f);
                    } else {
                        Ko[oidx] = f2bf(outv);
                    }
                }
            }
        }
    }
}

// ---------------- Flash attention (causal, paired q-tiles, swapped QK^T) --------------
// Swapped MFMA: sc = mfma(Kfrag, Qfrag) -> P[k][q] with q = lane&15, k = nb*16+4*hi+r.
// Softmax row is in-register (16 vals) + 2 shfl_xor across hi-lanes. P packed to LDS as
// b32 pairs in P~[q][k] layout; PV reads it as the A-operand (q rows) like before.
__device__ __forceinline__ void attn_tile_compute(
    const bf16x8 q0, const bf16x8 q1,
    const short (*Ks)[LDP], const short (*Vts)[LDP], short* __restrict__ Pw,
    const int lane, const int w, const bool diag,
    float& m_r, float& l_r, f32x4* __restrict__ o_acc) {
    const int lo = lane & 15, hi = lane >> 4;

    f32x4 sc[4];
#pragma unroll
    for (int nb = 0; nb < 4; nb++) sc[nb] = {0.f, 0.f, 0.f, 0.f};
#pragma unroll
    for (int nb = 0; nb < 4; nb++) {
        bf16x8 k0 = *reinterpret_cast<const bf16x8*>(&Ks[nb * 16 + lo][hi * 8]);
        sc[nb] = __builtin_amdgcn_mfma_f32_16x16x32_bf16(k0, q0, sc[nb], 0, 0, 0);
        bf16x8 k1 = *reinterpret_cast<const bf16x8*>(&Ks[nb * 16 + lo][32 + hi * 8]);
        sc[nb] = __builtin_amdgcn_mfma_f32_16x16x32_bf16(k1, q1, sc[nb], 0, 0, 0);
    }
    if (diag) {
        const int q_ = w * 16 + lo;          // q-local within 64-row tile (q col = lane&15)
        const int kb = (hi << 2);
#pragma unroll
        for (int nb = 0; nb < 4; nb++) {
            const int k_ = nb * 16 + kb;     // k-local = nb*16 + 4*hi + r
#pragma unroll
            for (int r = 0; r < 4; r++)
                if (k_ + r > q_) sc[nb][r] = -1e30f;
        }
    }

    // in-register row reduction (row = all k for this lane's q)
    float mx = sc[0][0];
#pragma unroll
    for (int nb = 0; nb < 4; nb++)
#pragma unroll
        for (int r = 0; r < 4; r++) mx = fmaxf(mx, sc[nb][r]);
    mx = fmaxf(mx, __shfl_xor(mx, 16, 64));
    mx = fmaxf(mx, __shfl_xor(mx, 32, 64));

    const float mnew = fmaxf(m_r, mx);
    const float alpha = __expf(m_r - mnew);
    m_r = mnew;

    float rs = 0.f;
#pragma unroll
    for (int nb = 0; nb < 4; nb++)
#pragma unroll
        for (int r = 0; r < 4; r++) {
            float e = __expf(sc[nb][r] - mnew);
            sc[nb][r] = e;
            rs += e;
        }
    rs += __shfl_xor(rs, 16, 64);
    rs += __shfl_xor(rs, 32, 64);
    l_r = l_r * alpha + rs;

    // rescale O: o_acc rows are q = 4*hi + r -> fetch alpha for those q's
    float alpha_q[4];
#pragma unroll
    for (int r = 0; r < 4; r++) alpha_q[r] = __shfl(alpha, (hi << 2) + r, 64);
#pragma unroll
    for (int db = 0; db < 4; db++)
#pragma unroll
        for (int r = 0; r < 4; r++) o_acc[db][r] *= alpha_q[r];

    // pack P -> LDS: P~[q=lo][k], pairs along k; word idx = lo*36 + nb*8 + 2*hi + rr
    unsigned int* Pw32 = reinterpret_cast<unsigned int*>(Pw);
#pragma unroll
    for (int nb = 0; nb < 4; nb++)
#pragma unroll
        for (int rr = 0; rr < 2; rr++) {
            unsigned int u = (unsigned int)(unsigned short)f2bf(sc[nb][2 * rr]) |
                             ((unsigned int)(unsigned short)f2bf(sc[nb][2 * rr + 1]) << 16);
            Pw32[lo * (LDP / 2) + nb * 8 + (hi << 1) + rr] = u;
        }

#pragma unroll
    for (int kk = 0; kk < 2; kk++) {
        bf16x8 pa = *reinterpret_cast<const bf16x8*>(&Pw[lo * LDP + kk * 32 + hi * 8]);
#pragma unroll
        for (int db = 0; db < 4; db++) {
            const int d = db * 16 + lo;
            const int tsw = (kk * 32 + hi * 8) ^ ((((d >> 3) & 7)) << 3);
            bf16x8 vb = *reinterpret_cast<const bf16x8*>(&Vts[d][tsw]);
            o_acc[db] = __builtin_amdgcn_mfma_f32_16x16x32_bf16(pa, vb, o_acc[db], 0, 0, 0);
        }
    }
}

__global__ __launch_bounds__(256) void attn_kernel(
    const short* __restrict__ Q, const short* __restrict__ K,
    const short* __restrict__ V, short* __restrict__ O) {
    __shared__ short Ks[64][LDP];
    __shared__ short Vts[64][LDP];
    __shared__ short Ps[4][16][LDP];

    const int tid = threadIdx.x;
    const int lane = tid & 63;
    const int w = tid >> 6;
    const int lo = lane & 15, hi = lane >> 4;
    const int pi = blockIdx.x;          // 0..15
    const int qa = pi, qb = 31 - pi;    // paired q-tiles
    const int bh = blockIdx.y;
    const int b_ = bh >> 4, h = bh & 15;
    const size_t base = (size_t)bh * 2048 * 64;

    // Q-hoist: stage both Q tiles through Ks, keep fragments in registers
    bf16x8 qaf0, qaf1, qbf0, qbf1;
    {
        const int row = tid >> 2, cb = (tid & 3) * 16;
        const short* srcA = Q + base + (size_t)(qa * 64 + row) * 64 + cb;
        *reinterpret_cast<bf16x8*>(&Ks[row][cb]) = *reinterpret_cast<const bf16x8*>(srcA);
        *reinterpret_cast<bf16x8*>(&Ks[row][cb + 8]) = *reinterpret_cast<const bf16x8*>(srcA + 8);
        __syncthreads();
        qaf0 = *reinterpret_cast<const bf16x8*>(&Ks[w * 16 + lo][hi * 8]);
        qaf1 = *reinterpret_cast<const bf16x8*>(&Ks[w * 16 + lo][32 + hi * 8]);
        __syncthreads();
        const short* srcB = Q + base + (size_t)(qb * 64 + row) * 64 + cb;
        *reinterpret_cast<bf16x8*>(&Ks[row][cb]) = *reinterpret_cast<const bf16x8*>(srcB);
        *reinterpret_cast<bf16x8*>(&Ks[row][cb + 8]) = *reinterpret_cast<const bf16x8*>(srcB + 8);
        __syncthreads();
        qbf0 = *reinterpret_cast<const bf16x8*>(&Ks[w * 16 + lo][hi * 8]);
        qbf1 = *reinterpret_cast<const bf16x8*>(&Ks[w * 16 + lo][32 + hi * 8]);
    }

    float m_a = -1e30f, l_a = 0.f, m_b = -1e30f, l_b = 0.f;
    f32x4 o_a[4], o_b[4];
#pragma unroll
    for (int db = 0; db < 4; db++) { o_a[db] = {0.f, 0.f, 0.f, 0.f}; o_b[db] = {0.f, 0.f, 0.f, 0.f}; }

    for (int j = 0; j <= qb; j++) {
        const int jbase = j * 64;
        __syncthreads();
        {
            const int row = tid >> 2, cb = (tid & 3) * 16;
            const short* src = K + base + (size_t)(jbase + row) * 64 + cb;
            *reinterpret_cast<bf16x8*>(&Ks[row][cb]) = *reinterpret_cast<const bf16x8*>(src);
            *reinterpret_cast<bf16x8*>(&Ks[row][cb + 8]) = *reinterpret_cast<const bf16x8*>(src + 8);
        }
#pragma unroll
        for (int half = 0; half < 2; half++) {
            const int kv = (tid >> 3) + half * 32;
            const int db8 = (tid & 7) * 8;
            const int swz = (tid & 7) << 3;
            bf16x8 v = *reinterpret_cast<const bf16x8*>(V + base + (size_t)(jbase + kv) * 64 + db8);
            const int tsw = kv ^ swz;
#pragma unroll
            for (int i = 0; i < 8; i++) Vts[db8 + i][tsw] = v[i];
        }
        __syncthreads();

        attn_tile_compute(qbf0, qbf1, Ks, Vts, &Ps[w][0][0], lane, w, j == qb, m_b, l_b, o_b);
        if (j <= qa)
            attn_tile_compute(qaf0, qaf1, Ks, Vts, &Ps[w][0][0], lane, w, j == qa, m_a, l_a, o_a);
    }

    // O rows are q = 4*hi + r -> fetch inverse-l for those q's
    float inva[4], invb[4];
#pragma unroll
    for (int r = 0; r < 4; r++) {
        inva[r] = 1.f / __shfl(l_a, (hi << 2) + r, 64);
        invb[r] = 1.f / __shfl(l_b, (hi << 2) + r, 64);
    }

    short* Op = O + ((size_t)b_ * 2048) * 1024 + (size_t)h * 64;
#pragma unroll
    for (int r = 0; r < 4; r++) {
        const int rowa = qa * 64 + w * 16 + (hi << 2) + r;
        const int rowb = qb * 64 + w * 16 + (hi << 2) + r;
#pragma unroll
        for (int db = 0; db < 4; db++) {
            Op[(size_t)rowa * 1024 + db * 16 + lo] = f2bf(o_a[db][r] * inva[r]);
            Op[(size_t)rowb * 1024 + db * 16 + lo] = f2bf(o_b[db][r] * invb[r]);
        }
    }
}

// ---------------- Out GEMM, global_load_lds staging ----------------
__global__ __launch_bounds__(256) void gemm_out(
    const short* __restrict__ A, const short* __restrict__ W,
    float* __restrict__ C) {
    __shared__ short As[128 * 64];
    __shared__ short Bs[128 * 64];
    const int tid = threadIdx.x;
    const int lane = tid & 63;
    const int w = tid >> 6;
    const int lo = lane & 15, hi = lane >> 4;
    const int wr = w >> 1, wc = w & 1;
    const int m0 = blockIdx.y * 128;
    const int n0 = blockIdx.x * 128;
    const int K = 1024;

    f32x4 acc[4][4];
#pragma unroll
    for (int i = 0; i < 4; i++)
#pragma unroll
        for (int j = 0; j < 4; j++) acc[i][j] = {0.f, 0.f, 0.f, 0.f};

    const int srow = w * 8 + (lane >> 3);
    const int sc8 = (lane & 7) * 8;
    const short* gA = A + (size_t)(m0 + srow) * K + sc8;
    const short* gB = W + (size_t)(n0 + srow) * K + sc8;

    for (int k0 = 0; k0 < K; k0 += 64) {
        __syncthreads();
#pragma unroll
        for (int it = 0; it < 4; it++)
            GLDS(gA + k0 + (size_t)it * 32 * K, (char*)As + it * 4096 + w * 1024);
#pragma unroll
        for (int it = 0; it < 4; it++)
            GLDS(gB + k0 + (size_t)it * 32 * K, (char*)Bs + it * 4096 + w * 1024);
        __syncthreads();
#pragma unroll
        for (int kk = 0; kk < 2; kk++) {
            bf16x8 a[4], b[4];
#pragma unroll
            for (int mi = 0; mi < 4; mi++)
                a[mi] = *reinterpret_cast<const bf16x8*>(
                    &As[(wr * 64 + mi * 16 + lo) * 64 + kk * 32 + hi * 8]);
#pragma unroll
            for (int ni = 0; ni < 4; ni++)
                b[ni] = *reinterpret_cast<const bf16x8*>(
                    &Bs[(wc * 64 + ni * 16 + lo) * 64 + kk * 32 + hi * 8]);
#pragma unroll
            for (int mi = 0; mi < 4; mi++)
#pragma unroll
                for (int ni = 0; ni < 4; ni++)
                    acc[mi][ni] = __builtin_amdgcn_mfma_f32_16x16x32_bf16(
                        a[mi], b[ni], acc[mi][ni], 0, 0, 0);
        }
    }

#pragma unroll
    for (int mi = 0; mi < 4; mi++) {
#pragma unroll
        for (int r = 0; r < 4; r++) {
            const int m = m0 + wr * 64 + mi * 16 + (hi << 2) + r;
#pragma unroll
            for (int ni = 0; ni < 4; ni++) {
                const int n = n0 + wc * 64 + ni * 16 + lo;
                C[(size_t)m * 1024 + n] = acc[mi][ni][r];
            }
        }
    }
}

extern "C" void kernel_launch(void* const* d_in, const int* in_sizes, int n_in,
                              void* d_out, int out_size, void* d_ws, size_t ws_size,
                              hipStream_t stream) {
    const float* x = (const float*)d_in[0];
    const float* wQKV = (const float*)d_in[1];
    const float* wOut = (const float*)d_in[2];
    const float* cosT = (const float*)d_in[3];
    const float* sinT = (const float*)d_in[4];
    float* out = (float*)d_out;

    char* ws = (char*)d_ws;
    const size_t MB = 1024 * 1024;
    short* xb    = (short*)(ws);             // 8MB
    short* wqkvb = (short*)(ws + 8 * MB);    // 6MB
    short* woutb = (short*)(ws + 14 * MB);   // 2MB
    short* Qbuf  = (short*)(ws + 16 * MB);   // 8MB
    short* Kbuf  = (short*)(ws + 24 * MB);   // 8MB
    short* Vbuf  = (short*)(ws + 32 * MB);   // 8MB
    short* Obuf  = (short*)(ws + 40 * MB);   // 8MB (attn out, bf16)

    cvt_kernel<<<4096, 256, 0, stream>>>(x, xb, 1048576);
    cvt_kernel<<<3072, 256, 0, stream>>>(wQKV, wqkvb, 786432);
    cvt_kernel<<<1024, 256, 0, stream>>>(wOut, woutb, 262144);

    gemm_qkv_rope<<<dim3(24, 32), 256, 0, stream>>>(xb, wqkvb, cosT, sinT, Qbuf, Kbuf, Vbuf);
    attn_kernel<<<dim3(16, 32), 256, 0, stream>>>(Qbuf, Kbuf, Vbuf, Obuf);
    gemm_out<<<dim3(8, 32), 256, 0, stream>>>(Obuf, woutb, out);
}

// Round 6
// 161.799 us; speedup vs baseline: 1.2937x; 1.0512x over previous
//
#include <hip/hip_runtime.h>
#include <hip/hip_bf16.h>

typedef __attribute__((ext_vector_type(8))) short bf16x8;
typedef __attribute__((ext_vector_type(4))) short s16x4;
typedef __attribute__((ext_vector_type(4))) float f32x4;

__device__ __forceinline__ short f2bf(float f) {
    unsigned int u = __builtin_bit_cast(unsigned int, f);
    u += 0x7fffu + ((u >> 16) & 1u);
    return (short)(u >> 16);
}

#define GLDS(g, l) __builtin_amdgcn_global_load_lds( \
    (__attribute__((address_space(1))) void*)(g),    \
    (__attribute__((address_space(3))) void*)(l), 16, 0, 0)

// ---------------- fp32 -> bf16 convert ----------------
__global__ __launch_bounds__(256) void cvt_kernel(const float* __restrict__ in,
                                                  short* __restrict__ out, int n4) {
    int i = blockIdx.x * 256 + threadIdx.x;
    if (i >= n4) return;
    float4 v = reinterpret_cast<const float4*>(in)[i];
    s16x4 r = { f2bf(v.x), f2bf(v.y), f2bf(v.z), f2bf(v.w) };
    reinterpret_cast<s16x4*>(out)[i] = r;
}

#define LDP 72

// ---------------- QKV GEMM (+RoPE epilogue), 256x256 tile, 8 waves ----------------
// X: (4096,1024) bf16; W: (3072,1024) bf16 (as W^T). 192 blocks, XCD-chunked swizzle.
__global__ __launch_bounds__(512, 2) void gemm_qkv_rope(
    const short* __restrict__ X, const short* __restrict__ W,
    const float* __restrict__ cosT, const float* __restrict__ sinT,
    short* __restrict__ Qo, short* __restrict__ Ko, short* __restrict__ Vo) {
    __shared__ short As[256 * 64];   // linear, row-major [256][64]
    __shared__ short Bs[256 * 64];
    const int tid = threadIdx.x;
    const int lane = tid & 63;
    const int w = tid >> 6;              // 0..7
    const int lo = lane & 15, hi = lane >> 4;
    const int wr = w >> 2, wc = w & 3;   // 2 (M) x 4 (N) waves
    // bijective XCD-chunked swizzle (nwg=192, 192%8==0): XCD c gets wg in [c*24,(c+1)*24)
    const int lin = blockIdx.x;
    const int wg = (lin & 7) * 24 + (lin >> 3);
    const int n0 = (wg % 12) * 256;
    const int m0 = (wg / 12) * 256;
    const int K = 1024;

    f32x4 acc[8][4];
#pragma unroll
    for (int i = 0; i < 8; i++)
#pragma unroll
        for (int j = 0; j < 4; j++) acc[i][j] = {0.f, 0.f, 0.f, 0.f};

    // staging: per GLDS round, 512 threads cover 64 rows x 64 cols (16B/lane)
    const int srow = w * 8 + (lane >> 3);      // 0..63
    const int sc8 = (lane & 7) * 8;
    const short* gA = X + (size_t)(m0 + srow) * K + sc8;
    const short* gB = W + (size_t)(n0 + srow) * K + sc8;

    for (int k0 = 0; k0 < K; k0 += 64) {
        __syncthreads();
#pragma unroll
        for (int it = 0; it < 4; it++)
            GLDS(gA + k0 + (size_t)it * 64 * K, (char*)As + it * 8192 + w * 1024);
#pragma unroll
        for (int it = 0; it < 4; it++)
            GLDS(gB + k0 + (size_t)it * 64 * K, (char*)Bs + it * 8192 + w * 1024);
        __syncthreads();
#pragma unroll
        for (int kk = 0; kk < 2; kk++) {
            bf16x8 a[8], b[4];
#pragma unroll
            for (int mi = 0; mi < 8; mi++)
                a[mi] = *reinterpret_cast<const bf16x8*>(
                    &As[(wr * 128 + mi * 16 + lo) * 64 + kk * 32 + hi * 8]);
#pragma unroll
            for (int ni = 0; ni < 4; ni++)
                b[ni] = *reinterpret_cast<const bf16x8*>(
                    &Bs[(wc * 64 + ni * 16 + lo) * 64 + kk * 32 + hi * 8]);
#pragma unroll
            for (int mi = 0; mi < 8; mi++)
#pragma unroll
                for (int ni = 0; ni < 4; ni++)
                    acc[mi][ni] = __builtin_amdgcn_mfma_f32_16x16x32_bf16(
                        a[mi], b[ni], acc[mi][ni], 0, 0, 0);
        }
    }

    const int region = n0 >> 10;  // 0=q, 1=k, 2=v (256-tiles don't straddle 1024)
#pragma unroll
    for (int mi = 0; mi < 8; mi++) {
#pragma unroll
        for (int r = 0; r < 4; r++) {
            const int m = m0 + wr * 128 + mi * 16 + (hi << 2) + r;
            const int b_ = m >> 11;
            const int s_ = m & 2047;
#pragma unroll
            for (int ni = 0; ni < 4; ni++) {
                float v = acc[mi][ni][r];
                const int n = n0 + wc * 64 + ni * 16 + lo;
                const int c = n & 1023;
                const int h = c >> 6;
                const int d = c & 63;
                const size_t oidx = ((size_t)(b_ * 16 + h) * 2048 + s_) * 64 + d;
                if (region == 2) {
                    Vo[oidx] = f2bf(v);
                } else {
                    float other = __shfl_xor(v, 1, 64);
                    const int i2 = d >> 1;
                    float cs = cosT[s_ * 32 + i2];
                    float sn = sinT[s_ * 32 + i2];
                    float outv = (d & 1) ? (v * cs + other * sn) : (v * cs - other * sn);
                    if (region == 0) {
                        Qo[oidx] = f2bf(outv * 0.125f);
                    } else {
                        Ko[oidx] = f2bf(outv);
                    }
                }
            }
        }
    }
}

// ---------------- Flash attention (causal, paired q-tiles, swapped QK^T, dbuf) -------
__device__ __forceinline__ void attn_tile_compute(
    const bf16x8 q0, const bf16x8 q1,
    const short (*Ks)[LDP], const short (*Vts)[LDP], short* __restrict__ Pw,
    const int lane, const int w, const bool diag,
    float& m_r, float& l_r, f32x4* __restrict__ o_acc) {
    const int lo = lane & 15, hi = lane >> 4;

    f32x4 sc[4];
#pragma unroll
    for (int nb = 0; nb < 4; nb++) sc[nb] = {0.f, 0.f, 0.f, 0.f};
#pragma unroll
    for (int nb = 0; nb < 4; nb++) {
        bf16x8 k0 = *reinterpret_cast<const bf16x8*>(&Ks[nb * 16 + lo][hi * 8]);
        sc[nb] = __builtin_amdgcn_mfma_f32_16x16x32_bf16(k0, q0, sc[nb], 0, 0, 0);
        bf16x8 k1 = *reinterpret_cast<const bf16x8*>(&Ks[nb * 16 + lo][32 + hi * 8]);
        sc[nb] = __builtin_amdgcn_mfma_f32_16x16x32_bf16(k1, q1, sc[nb], 0, 0, 0);
    }
    if (diag) {
        const int q_ = w * 16 + lo;
        const int kb = (hi << 2);
#pragma unroll
        for (int nb = 0; nb < 4; nb++) {
            const int k_ = nb * 16 + kb;
#pragma unroll
            for (int r = 0; r < 4; r++)
                if (k_ + r > q_) sc[nb][r] = -1e30f;
        }
    }

    float mx = sc[0][0];
#pragma unroll
    for (int nb = 0; nb < 4; nb++)
#pragma unroll
        for (int r = 0; r < 4; r++) mx = fmaxf(mx, sc[nb][r]);
    mx = fmaxf(mx, __shfl_xor(mx, 16, 64));
    mx = fmaxf(mx, __shfl_xor(mx, 32, 64));

    const float mnew = fmaxf(m_r, mx);
    const float alpha = __expf(m_r - mnew);
    m_r = mnew;

    float rs = 0.f;
#pragma unroll
    for (int nb = 0; nb < 4; nb++)
#pragma unroll
        for (int r = 0; r < 4; r++) {
            float e = __expf(sc[nb][r] - mnew);
            sc[nb][r] = e;
            rs += e;
        }
    rs += __shfl_xor(rs, 16, 64);
    rs += __shfl_xor(rs, 32, 64);
    l_r = l_r * alpha + rs;

    float alpha_q[4];
#pragma unroll
    for (int r = 0; r < 4; r++) alpha_q[r] = __shfl(alpha, (hi << 2) + r, 64);
#pragma unroll
    for (int db = 0; db < 4; db++)
#pragma unroll
        for (int r = 0; r < 4; r++) o_acc[db][r] *= alpha_q[r];

    unsigned int* Pw32 = reinterpret_cast<unsigned int*>(Pw);
#pragma unroll
    for (int nb = 0; nb < 4; nb++)
#pragma unroll
        for (int rr = 0; rr < 2; rr++) {
            unsigned int u = (unsigned int)(unsigned short)f2bf(sc[nb][2 * rr]) |
                             ((unsigned int)(unsigned short)f2bf(sc[nb][2 * rr + 1]) << 16);
            Pw32[lo * (LDP / 2) + nb * 8 + (hi << 1) + rr] = u;
        }

#pragma unroll
    for (int kk = 0; kk < 2; kk++) {
        bf16x8 pa = *reinterpret_cast<const bf16x8*>(&Pw[lo * LDP + kk * 32 + hi * 8]);
#pragma unroll
        for (int db = 0; db < 4; db++) {
            const int d = db * 16 + lo;
            const int tsw = (kk * 32 + hi * 8) ^ ((((d >> 3) & 7)) << 3);
            bf16x8 vb = *reinterpret_cast<const bf16x8*>(&Vts[d][tsw]);
            o_acc[db] = __builtin_amdgcn_mfma_f32_16x16x32_bf16(pa, vb, o_acc[db], 0, 0, 0);
        }
    }
}

__global__ __launch_bounds__(256) void attn_kernel(
    const short* __restrict__ Q, const short* __restrict__ K,
    const short* __restrict__ V, short* __restrict__ O) {
    __shared__ short Ks[2][64][LDP];
    __shared__ short Vts[2][64][LDP];
    __shared__ short Ps[4][16][LDP];

    const int tid = threadIdx.x;
    const int lane = tid & 63;
    const int w = tid >> 6;
    const int lo = lane & 15, hi = lane >> 4;
    // bijective XCD-chunked swizzle (nwg=512): XCD c gets 4 complete bh groups
    const int lin = blockIdx.x;
    const int wg = (lin & 7) * 64 + (lin >> 3);
    const int pi = wg & 15;
    const int bh = wg >> 4;
    const int qa = pi, qb = 31 - pi;
    const int b_ = bh >> 4, h = bh & 15;
    const size_t base = (size_t)bh * 2048 * 64;

    // Q-hoist: stage both Q tiles through Ks[0], keep fragments in registers
    bf16x8 qaf0, qaf1, qbf0, qbf1;
    {
        const int row = tid >> 2, cb = (tid & 3) * 16;
        const short* srcA = Q + base + (size_t)(qa * 64 + row) * 64 + cb;
        *reinterpret_cast<bf16x8*>(&Ks[0][row][cb]) = *reinterpret_cast<const bf16x8*>(srcA);
        *reinterpret_cast<bf16x8*>(&Ks[0][row][cb + 8]) = *reinterpret_cast<const bf16x8*>(srcA + 8);
        __syncthreads();
        qaf0 = *reinterpret_cast<const bf16x8*>(&Ks[0][w * 16 + lo][hi * 8]);
        qaf1 = *reinterpret_cast<const bf16x8*>(&Ks[0][w * 16 + lo][32 + hi * 8]);
        __syncthreads();
        const short* srcB = Q + base + (size_t)(qb * 64 + row) * 64 + cb;
        *reinterpret_cast<bf16x8*>(&Ks[0][row][cb]) = *reinterpret_cast<const bf16x8*>(srcB);
        *reinterpret_cast<bf16x8*>(&Ks[0][row][cb + 8]) = *reinterpret_cast<const bf16x8*>(srcB + 8);
        __syncthreads();
        qbf0 = *reinterpret_cast<const bf16x8*>(&Ks[0][w * 16 + lo][hi * 8]);
        qbf1 = *reinterpret_cast<const bf16x8*>(&Ks[0][w * 16 + lo][32 + hi * 8]);
        __syncthreads();   // all qbf reads done before loop overwrites Ks[0]
    }

    float m_a = -1e30f, l_a = 0.f, m_b = -1e30f, l_b = 0.f;
    f32x4 o_a[4], o_b[4];
#pragma unroll
    for (int db = 0; db < 4; db++) { o_a[db] = {0.f, 0.f, 0.f, 0.f}; o_b[db] = {0.f, 0.f, 0.f, 0.f}; }

    // register prefetch of tile j=0
    const int krow = tid >> 2, kcb = (tid & 3) * 16;
    const int vkv = tid >> 3, vdb8 = (tid & 7) * 8;
    const int vswz = (tid & 7) << 3;
    bf16x8 kr0, kr1, vr0, vr1;
    kr0 = *reinterpret_cast<const bf16x8*>(K + base + (size_t)krow * 64 + kcb);
    kr1 = *reinterpret_cast<const bf16x8*>(K + base + (size_t)krow * 64 + kcb + 8);
    vr0 = *reinterpret_cast<const bf16x8*>(V + base + (size_t)vkv * 64 + vdb8);
    vr1 = *reinterpret_cast<const bf16x8*>(V + base + (size_t)(vkv + 32) * 64 + vdb8);

    int c = 0;
    for (int j = 0; j <= qb; j++) {
        // write prefetched tile j into LDS buffer c
        *reinterpret_cast<bf16x8*>(&Ks[c][krow][kcb]) = kr0;
        *reinterpret_cast<bf16x8*>(&Ks[c][krow][kcb + 8]) = kr1;
        {
            const int t0 = vkv ^ vswz;
            const int t1 = (vkv + 32) ^ vswz;
#pragma unroll
            for (int i = 0; i < 8; i++) Vts[c][vdb8 + i][t0] = vr0[i];
#pragma unroll
            for (int i = 0; i < 8; i++) Vts[c][vdb8 + i][t1] = vr1[i];
        }
        __syncthreads();
        if (j < qb) {
            const size_t jb2 = (size_t)(j + 1) * 64;
            kr0 = *reinterpret_cast<const bf16x8*>(K + base + (jb2 + krow) * 64 + kcb);
            kr1 = *reinterpret_cast<const bf16x8*>(K + base + (jb2 + krow) * 64 + kcb + 8);
            vr0 = *reinterpret_cast<const bf16x8*>(V + base + (jb2 + vkv) * 64 + vdb8);
            vr1 = *reinterpret_cast<const bf16x8*>(V + base + (jb2 + vkv + 32) * 64 + vdb8);
        }

        attn_tile_compute(qbf0, qbf1, Ks[c], Vts[c], &Ps[w][0][0], lane, w, j == qb, m_b, l_b, o_b);
        if (j <= qa)
            attn_tile_compute(qaf0, qaf1, Ks[c], Vts[c], &Ps[w][0][0], lane, w, j == qa, m_a, l_a, o_a);
        c ^= 1;
    }

    float inva[4], invb[4];
#pragma unroll
    for (int r = 0; r < 4; r++) {
        inva[r] = 1.f / __shfl(l_a, (hi << 2) + r, 64);
        invb[r] = 1.f / __shfl(l_b, (hi << 2) + r, 64);
    }

    short* Op = O + ((size_t)b_ * 2048) * 1024 + (size_t)h * 64;
#pragma unroll
    for (int r = 0; r < 4; r++) {
        const int rowa = qa * 64 + w * 16 + (hi << 2) + r;
        const int rowb = qb * 64 + w * 16 + (hi << 2) + r;
#pragma unroll
        for (int db = 0; db < 4; db++) {
            Op[(size_t)rowa * 1024 + db * 16 + lo] = f2bf(o_a[db][r] * inva[r]);
            Op[(size_t)rowb * 1024 + db * 16 + lo] = f2bf(o_b[db][r] * invb[r]);
        }
    }
}

// ---------------- Out GEMM, global_load_lds staging, XCD swizzle ----------------
__global__ __launch_bounds__(256) void gemm_out(
    const short* __restrict__ A, const short* __restrict__ W,
    float* __restrict__ C) {
    __shared__ short As[128 * 64];
    __shared__ short Bs[128 * 64];
    const int tid = threadIdx.x;
    const int lane = tid & 63;
    const int w = tid >> 6;
    const int lo = lane & 15, hi = lane >> 4;
    const int wr = w >> 1, wc = w & 1;
    // bijective XCD-chunked swizzle (nwg=256): XCD c gets 4 m-rows x all 8 n
    const int lin = blockIdx.x;
    const int wg = (lin & 7) * 32 + (lin >> 3);
    const int n0 = (wg & 7) * 128;
    const int m0 = (wg >> 3) * 128;
    const int K = 1024;

    f32x4 acc[4][4];
#pragma unroll
    for (int i = 0; i < 4; i++)
#pragma unroll
        for (int j = 0; j < 4; j++) acc[i][j] = {0.f, 0.f, 0.f, 0.f};

    const int srow = w * 8 + (lane >> 3);
    const int sc8 = (lane & 7) * 8;
    const short* gA = A + (size_t)(m0 + srow) * K + sc8;
    const short* gB = W + (size_t)(n0 + srow) * K + sc8;

    for (int k0 = 0; k0 < K; k0 += 64) {
        __syncthreads();
#pragma unroll
        for (int it = 0; it < 4; it++)
            GLDS(gA + k0 + (size_t)it * 32 * K, (char*)As + it * 4096 + w * 1024);
#pragma unroll
        for (int it = 0; it < 4; it++)
            GLDS(gB + k0 + (size_t)it * 32 * K, (char*)Bs + it * 4096 + w * 1024);
        __syncthreads();
#pragma unroll
        for (int kk = 0; kk < 2; kk++) {
            bf16x8 a[4], b[4];
#pragma unroll
            for (int mi = 0; mi < 4; mi++)
                a[mi] = *reinterpret_cast<const bf16x8*>(
                    &As[(wr * 64 + mi * 16 + lo) * 64 + kk * 32 + hi * 8]);
#pragma unroll
            for (int ni = 0; ni < 4; ni++)
                b[ni] = *reinterpret_cast<const bf16x8*>(
                    &Bs[(wc * 64 + ni * 16 + lo) * 64 + kk * 32 + hi * 8]);
#pragma unroll
            for (int mi = 0; mi < 4; mi++)
#pragma unroll
                for (int ni = 0; ni < 4; ni++)
                    acc[mi][ni] = __builtin_amdgcn_mfma_f32_16x16x32_bf16(
                        a[mi], b[ni], acc[mi][ni], 0, 0, 0);
        }
    }

#pragma unroll
    for (int mi = 0; mi < 4; mi++) {
#pragma unroll
        for (int r = 0; r < 4; r++) {
            const int m = m0 + wr * 64 + mi * 16 + (hi << 2) + r;
#pragma unroll
            for (int ni = 0; ni < 4; ni++) {
                const int n = n0 + wc * 64 + ni * 16 + lo;
                C[(size_t)m * 1024 + n] = acc[mi][ni][r];
            }
        }
    }
}

extern "C" void kernel_launch(void* const* d_in, const int* in_sizes, int n_in,
                              void* d_out, int out_size, void* d_ws, size_t ws_size,
                              hipStream_t stream) {
    const float* x = (const float*)d_in[0];
    const float* wQKV = (const float*)d_in[1];
    const float* wOut = (const float*)d_in[2];
    const float* cosT = (const float*)d_in[3];
    const float* sinT = (const float*)d_in[4];
    float* out = (float*)d_out;

    char* ws = (char*)d_ws;
    const size_t MB = 1024 * 1024;
    short* xb    = (short*)(ws);             // 8MB
    short* wqkvb = (short*)(ws + 8 * MB);    // 6MB
    short* woutb = (short*)(ws + 14 * MB);   // 2MB
    short* Qbuf  = (short*)(ws + 16 * MB);   // 8MB
    short* Kbuf  = (short*)(ws + 24 * MB);   // 8MB
    short* Vbuf  = (short*)(ws + 32 * MB);   // 8MB
    short* Obuf  = (short*)(ws + 40 * MB);   // 8MB (attn out, bf16)

    cvt_kernel<<<4096, 256, 0, stream>>>(x, xb, 1048576);
    cvt_kernel<<<3072, 256, 0, stream>>>(wQKV, wqkvb, 786432);
    cvt_kernel<<<1024, 256, 0, stream>>>(wOut, woutb, 262144);

    gemm_qkv_rope<<<192, 512, 0, stream>>>(xb, wqkvb, cosT, sinT, Qbuf, Kbuf, Vbuf);
    attn_kernel<<<512, 256, 0, stream>>>(Qbuf, Kbuf, Vbuf, Obuf);
    gemm_out<<<256, 256, 0, stream>>>(Obuf, woutb, out);
}